// Round 13
// baseline (29.038 us; speedup 1.0000x reference)
//
#include <hip/hip_runtime.h>

// Problem constants (match reference setup_inputs)
#define B_ 8
#define T_ 1024
#define S_ 4096
#define H_ 256

#define STRIP 64           // tokens per K1 block
#define CHUNK 128          // tag rows per early-exit check (4 waves x 32 rows)
#define NCHUNK (T_ / CHUNK)

// K1: top-down early-exit column-max, TRUE register double-buffering.
// 512 blocks x 4 waves. Lane owns one token column; wave w owns 32 rows of
// each 128-row chunk (coalesced 256B row loads). Chunk loop unrolled x2 with
// alternating v/vn buffers and NO register copy: processing one buffer only
// waits vmcnt(32) while the other buffer's 32 loads stay in flight (R11's
// vn->v copy forced vmcnt(0) every chunk = pipeline drain, ~4 TB/s).
// Exit via per-chunk ballot + single barrier (ping-pong LDS slot).
__global__ void __launch_bounds__(256) colmax_dbuf_kernel(const float* __restrict__ ttt,
                                                          int* __restrict__ L,
                                                          int2* __restrict__ range) {
    __shared__ unsigned long long wmask[2][4];
    __shared__ int red[4][STRIP];
    const int strippos = blockIdx.x >> 3;
    const int b  = blockIdx.x & 7;
    const int s0 = strippos * STRIP;
    const int w    = threadIdx.x >> 6;
    const int lane = threadIdx.x & 63;

    // chunk k occupies rows [T - (k+1)*CHUNK, T - k*CHUNK), k = 0..NCHUNK-1
    const float* colbase = ttt + (size_t)b * T_ * S_ + s0 + lane;
    auto rowp = [&](int k) {                  // wave w's slice base of chunk k
        return colbase + (size_t)(T_ - (k + 1) * CHUNK + w * 32) * S_;
    };

    int best = -1;
    int par = 0;
    float v[32], vn[32];

    // prologue: chunk 0 -> v
    {
        const float* p = rowp(0);
#pragma unroll
        for (int j = 0; j < 32; ++j) v[j] = p[(size_t)j * S_];
    }

    for (int k = 0; k < NCHUNK; k += 2) {
        // ---- half A: chunk k in v ----
        if (k + 1 < NCHUNK) {                 // prefetch chunk k+1 -> vn
            const float* p = rowp(k + 1);
#pragma unroll
            for (int j = 0; j < 32; ++j) vn[j] = p[(size_t)j * S_];
        }
        {
            const int t0 = T_ - (k + 1) * CHUNK + w * 32;
            int lm = -1;
#pragma unroll
            for (int j = 0; j < 32; ++j)
                if (v[j] > 0.0f) lm = t0 + j; // ascending j -> in-chunk max
            best = max(best, lm);
        }
        wmask[par][w] = __ballot(best >= 0);
        __syncthreads();
        if ((wmask[par][0] | wmask[par][1] | wmask[par][2] | wmask[par][3]) == ~0ull)
            break;
        par ^= 1;
        if (k + 1 >= NCHUNK) break;

        // ---- half B: chunk k+1 in vn ----
        if (k + 2 < NCHUNK) {                 // prefetch chunk k+2 -> v
            const float* p = rowp(k + 2);
#pragma unroll
            for (int j = 0; j < 32; ++j) v[j] = p[(size_t)j * S_];
        }
        {
            const int t0 = T_ - (k + 2) * CHUNK + w * 32;
            int lm = -1;
#pragma unroll
            for (int j = 0; j < 32; ++j)
                if (vn[j] > 0.0f) lm = t0 + j;
            best = max(best, lm);
        }
        wmask[par][w] = __ballot(best >= 0);
        __syncthreads();
        if ((wmask[par][0] | wmask[par][1] | wmask[par][2] | wmask[par][3]) == ~0ull)
            break;
        par ^= 1;
    }

    // epilogue: cross-wave max-combine -> L, plus strip [Lmin,Lmax] -> range
    red[w][lane] = best;
    __syncthreads();
    if (threadIdx.x < STRIP) {                // exactly wave 0, all 64 lanes
        const int tid = threadIdx.x;
        int m = max(max(red[0][tid], red[1][tid]),
                    max(red[2][tid], red[3][tid]));
        L[b * S_ + s0 + tid] = m;
        int mn = (m < 0) ? 0x7fffffff : m;    // not-found -> +INF for min
        int mx = m;                           // not-found -1 never wins max
#pragma unroll
        for (int k = 32; k >= 1; k >>= 1) {
            mn = min(mn, __shfl_xor(mn, k));
            mx = max(mx, __shfl_xor(mx, k));
        }
        if (tid == 0) {
            int2 rg = {mn, mx};               // empty strip -> (INT_MAX,-1)
            range[b * (S_ / STRIP) + strippos] = rg;
        }
    }
}

// K2: range-filtered gather + mean + seq_emb (unchanged from R12, absmax 0.0).
__global__ void __launch_bounds__(256) gather_range_kernel(const float* __restrict__ inputs,
                                                           const int* __restrict__ L,
                                                           const int2* __restrict__ range,
                                                           const float* __restrict__ seq_emb,
                                                           float* __restrict__ out) {
    const int wid  = threadIdx.x >> 6;
    const int lane = threadIdx.x & 63;
    const int bt = blockIdx.x * 4 + wid;         // (b*T + t), 4 waves per block
    const int b = bt >> 10;
    const int t = bt & (T_ - 1);

    const float4* in4 = reinterpret_cast<const float4*>(inputs);

    int2 rg = range[b * (S_ / STRIP) + lane];    // lane = strip id (64 strips)
    unsigned long long smask = __ballot(rg.x <= t && t <= rg.y);

    float4 acc = {0.0f, 0.0f, 0.0f, 0.0f};
    int c = 0;

    while (smask) {                              // wave-uniform loop
        int strip = __ffsll(smask) - 1; smask &= smask - 1;
        int Lv = L[b * S_ + strip * STRIP + lane];
        unsigned long long bm = __ballot(Lv == t);
        while (bm) {
            int l = __ffsll(bm) - 1; bm &= bm - 1;
            int s = strip * STRIP + l;
            float4 r = in4[(size_t)(b * S_ + s) * (H_ / 4) + lane];
            acc.x += r.x; acc.y += r.y; acc.z += r.z; acc.w += r.w; c++;
        }
    }

    float inv = (c > 0) ? (1.0f / (float)c) : 0.0f;   // empty row -> just emb
    float4 e = reinterpret_cast<const float4*>(seq_emb)[t * (H_ / 4) + lane];
    float4 o;
    o.x = acc.x * inv + e.x;
    o.y = acc.y * inv + e.y;
    o.z = acc.z * inv + e.z;
    o.w = acc.w * inv + e.w;
    reinterpret_cast<float4*>(out)[(size_t)bt * (H_ / 4) + lane] = o;
}

extern "C" void kernel_launch(void* const* d_in, const int* in_sizes, int n_in,
                              void* d_out, int out_size, void* d_ws, size_t ws_size,
                              hipStream_t stream) {
    const float* inputs  = (const float*)d_in[0];   // [B,S,H]
    const float* ttt     = (const float*)d_in[1];   // [B,T,S]
    const float* seq_emb = (const float*)d_in[2];   // [T,H]
    float* out = (float*)d_out;                     // [B,T,H]

    int* L = (int*)d_ws;                            // B*S ints (128 KiB)
    int2* range = (int2*)(L + B_ * S_);             // 512 int2 (4 KiB)

    // K1: double-buffered early-exit column-max + strip ranges
    colmax_dbuf_kernel<<<B_ * (S_ / STRIP), 256, 0, stream>>>(ttt, L, range);

    // K2: range-filtered gather + mean + emb (B*T/4 blocks, 1 wave per row)
    gather_range_kernel<<<B_ * T_ / 4, 256, 0, stream>>>(inputs, L, range, seq_emb, out);
}